// Round 1
// baseline (401.722 us; speedup 1.0000x reference)
//
#include <hip/hip_runtime.h>

typedef float f32x4 __attribute__((ext_vector_type(4)));
typedef long i64;

#define KDIM 512
#define NDIM 512
#define LDS_STRIDE 520  // 512 + 8B pad: row-to-row bank offset = 2 -> conflict-free b64 frag reads

__device__ __forceinline__ float clamp448(float v) {
    return fminf(fmaxf(v, -448.0f), 448.0f);
}

// ---------------- Kernel 1: global abs-max of x (blocks 0..4095) and w (blocks 4096..4127) ----
__global__ __launch_bounds__(256) void amax_kernel(const float4* __restrict__ x,
                                                   const float4* __restrict__ w,
                                                   unsigned* __restrict__ scales) {
    const int tid = threadIdx.x;
    float m = 0.0f;
    if (blockIdx.x < 4096) {
        // x: 33,554,432 floats = 8,388,608 float4; 4096 blk * 256 thr * 8 iters
        int base = blockIdx.x * 256 + tid;
        #pragma unroll
        for (int j = 0; j < 8; ++j) {
            float4 v = x[base + j * 1048576];
            m = fmaxf(m, fmaxf(fmaxf(fabsf(v.x), fabsf(v.y)), fmaxf(fabsf(v.z), fabsf(v.w))));
        }
    } else {
        // w: 262,144 floats = 65,536 float4; 32 blk * 256 thr * 8 iters
        int base = (blockIdx.x - 4096) * 256 + tid;
        #pragma unroll
        for (int j = 0; j < 8; ++j) {
            float4 v = w[base + j * 8192];
            m = fmaxf(m, fmaxf(fmaxf(fabsf(v.x), fabsf(v.y)), fmaxf(fabsf(v.z), fabsf(v.w))));
        }
    }
    #pragma unroll
    for (int off = 32; off > 0; off >>= 1)
        m = fmaxf(m, __shfl_down(m, off, 64));
    __shared__ float red[4];
    const int wave = tid >> 6, lane = tid & 63;
    if (lane == 0) red[wave] = m;
    __syncthreads();
    if (tid == 0) {
        m = fmaxf(fmaxf(red[0], red[1]), fmaxf(red[2], red[3]));
        // all values >= 0 -> uint bit order == float order
        atomicMax(&scales[blockIdx.x < 4096 ? 0 : 1], __float_as_uint(m));
    }
}

// ---------------- Kernel 2: quantize weight [K,N] fp32 -> w_fp8 [N,K] e4m3 ------------------
__global__ __launch_bounds__(256) void wquant_kernel(const float* __restrict__ w,
                                                     const unsigned* __restrict__ scales,
                                                     unsigned* __restrict__ wq) {
    const int t = blockIdx.x * 256 + threadIdx.x;   // 65536 threads, 4 bytes each
    const int n = t >> 7;        // output row (N)
    const int kq = t & 127;      // u32 index within row
    const int k = kq << 2;
    const float ws = 448.0f / fmaxf(__uint_as_float(scales[1]), 1e-12f);
    float a0 = clamp448(w[(k + 0) * NDIM + n] * ws);
    float a1 = clamp448(w[(k + 1) * NDIM + n] * ws);
    float a2 = clamp448(w[(k + 2) * NDIM + n] * ws);
    float a3 = clamp448(w[(k + 3) * NDIM + n] * ws);
    int p = __builtin_amdgcn_cvt_pk_fp8_f32(a0, a1, 0, false);
    p = __builtin_amdgcn_cvt_pk_fp8_f32(a2, a3, p, true);
    wq[t] = (unsigned)p;
}

// ---------------- Kernel 3: fused x-quant (LDS staging) + fp8 MFMA GEMM + dequant ------------
// Block: 64 rows x full K=512. 4 waves, each 64x64 output per n-chunk, 2 chunks of 256 cols.
__global__ __launch_bounds__(256, 4) void gemm_kernel(const float* __restrict__ x,
                                                      const unsigned char* __restrict__ wq,
                                                      const unsigned* __restrict__ scales,
                                                      float* __restrict__ out) {
    __shared__ unsigned char lds_a[64 * LDS_STRIDE];  // 33,280 B
    const int tid = threadIdx.x;
    const long m0 = (long)blockIdx.x * 64;

    const float ax = fmaxf(__uint_as_float(scales[0]), 1e-12f);
    const float aw = fmaxf(__uint_as_float(scales[1]), 1e-12f);
    const float xs = 448.0f / ax;
    const float ws = 448.0f / aw;
    const float inv = (1.0f / xs) * (1.0f / ws);   // mirror reference dequant arithmetic

    // ---- stage: 64x512 fp32 -> fp8 into LDS (8,192 float4, 32 per thread, coalesced) ----
    const float4* xv = (const float4*)(x + m0 * KDIM);
    #pragma unroll 8
    for (int j = 0; j < 32; ++j) {
        int f4i = tid + 256 * j;
        float4 v = xv[f4i];
        int row = f4i >> 7;             // 128 float4 per row
        int colb = (f4i & 127) << 2;    // byte column
        float a0 = clamp448(v.x * xs);
        float a1 = clamp448(v.y * xs);
        float a2 = clamp448(v.z * xs);
        float a3 = clamp448(v.w * xs);
        int p = __builtin_amdgcn_cvt_pk_fp8_f32(a0, a1, 0, false);
        p = __builtin_amdgcn_cvt_pk_fp8_f32(a2, a3, p, true);
        *(unsigned*)&lds_a[row * LDS_STRIDE + colb] = (unsigned)p;
    }
    __syncthreads();

    const int wave = tid >> 6, lane = tid & 63;
    const int ln = lane & 15, lg = lane >> 4;
    const int kofs = lg * 8;

    for (int chunk = 0; chunk < 2; ++chunk) {
        const int nbase = chunk * 256 + wave * 64;
        f32x4 acc[4][4];
        #pragma unroll
        for (int a = 0; a < 4; ++a)
            #pragma unroll
            for (int b = 0; b < 4; ++b)
                acc[a][b] = (f32x4){0.0f, 0.0f, 0.0f, 0.0f};

        for (int ks = 0; ks < 16; ++ks) {
            const int kb = ks * 32 + kofs;
            i64 af[4], bf[4];
            #pragma unroll
            for (int t = 0; t < 4; ++t)
                af[t] = *(const i64*)&lds_a[(t * 16 + ln) * LDS_STRIDE + kb];
            #pragma unroll
            for (int t = 0; t < 4; ++t)
                bf[t] = *(const i64*)&wq[(nbase + t * 16 + ln) * KDIM + kb];
            #pragma unroll
            for (int tm = 0; tm < 4; ++tm)
                #pragma unroll
                for (int tn = 0; tn < 4; ++tn)
                    acc[tm][tn] = __builtin_amdgcn_mfma_f32_16x16x32_fp8_fp8(
                        af[tm], bf[tn], acc[tm][tn], 0, 0, 0);
        }

        // epilogue: C/D layout col = lane&15, row = (lane>>4)*4 + reg
        float* outp = out + m0 * NDIM;
        #pragma unroll
        for (int tm = 0; tm < 4; ++tm) {
            #pragma unroll
            for (int tn = 0; tn < 4; ++tn) {
                const int col = nbase + tn * 16 + ln;
                #pragma unroll
                for (int r = 0; r < 4; ++r) {
                    const int row = tm * 16 + lg * 4 + r;
                    outp[row * NDIM + col] = acc[tm][tn][r] * inv;
                }
            }
        }
    }
}

extern "C" void kernel_launch(void* const* d_in, const int* in_sizes, int n_in,
                              void* d_out, int out_size, void* d_ws, size_t ws_size,
                              hipStream_t stream) {
    const float* x = (const float*)d_in[0];
    const float* w = (const float*)d_in[1];
    float* out = (float*)d_out;
    unsigned* scales = (unsigned*)d_ws;                 // ws[0]=x_amax bits, ws[1]=w_amax bits
    unsigned char* wq = (unsigned char*)d_ws + 256;     // 262,144 B fp8 weight [N,K]
    const int M = in_sizes[0] / KDIM;                   // 65536

    hipMemsetAsync(d_ws, 0, 8, stream);                 // zero amax slots (ws is poisoned 0xAA)
    amax_kernel<<<4096 + 32, 256, 0, stream>>>((const float4*)x, (const float4*)w, scales);
    wquant_kernel<<<256, 256, 0, stream>>>(w, scales, (unsigned*)wq);
    gemm_kernel<<<M / 64, 256, 0, stream>>>(x, wq, scales, out);
}

// Round 2
// 357.873 us; speedup vs baseline: 1.1225x; 1.1225x over previous
//
#include <hip/hip_runtime.h>

typedef float f32x4 __attribute__((ext_vector_type(4)));
typedef long i64;

#define KDIM 512
#define NDIM 512
#define LDS_STRIDE 520   // A-tile: 512 + 8B pad -> row-to-row bank offset 2 -> conflict-free b64 reads
#define OUT_STRIDE 260   // epilogue tile: 256 + 4 floats pad -> 2-way banks (free)

__device__ __forceinline__ float clamp448(float v) {
    return fminf(fmaxf(v, -448.0f), 448.0f);
}

// ---------------- Kernel 1: global abs-max of x (blocks 0..4095) and w (blocks 4096..4127) ----
__global__ __launch_bounds__(256) void amax_kernel(const float4* __restrict__ x,
                                                   const float4* __restrict__ w,
                                                   unsigned* __restrict__ scales) {
    const int tid = threadIdx.x;
    float m = 0.0f;
    if (blockIdx.x < 4096) {
        int base = blockIdx.x * 256 + tid;
        #pragma unroll
        for (int j = 0; j < 8; ++j) {
            float4 v = x[base + j * 1048576];
            m = fmaxf(m, fmaxf(fmaxf(fabsf(v.x), fabsf(v.y)), fmaxf(fabsf(v.z), fabsf(v.w))));
        }
    } else {
        int base = (blockIdx.x - 4096) * 256 + tid;
        #pragma unroll
        for (int j = 0; j < 8; ++j) {
            float4 v = w[base + j * 8192];
            m = fmaxf(m, fmaxf(fmaxf(fabsf(v.x), fabsf(v.y)), fmaxf(fabsf(v.z), fabsf(v.w))));
        }
    }
    #pragma unroll
    for (int off = 32; off > 0; off >>= 1)
        m = fmaxf(m, __shfl_down(m, off, 64));
    __shared__ float red[4];
    const int wave = tid >> 6, lane = tid & 63;
    if (lane == 0) red[wave] = m;
    __syncthreads();
    if (tid == 0) {
        m = fmaxf(fmaxf(red[0], red[1]), fmaxf(red[2], red[3]));
        // all values >= 0 -> uint bit order == float order
        atomicMax(&scales[blockIdx.x < 4096 ? 0 : 1], __float_as_uint(m));
    }
}

// ---------------- Kernel 2: quantize weight [K,N] fp32 -> w_fp8 [N,K] e4m3 ------------------
// Coalesced float4 reads of w (1 MB fetched exactly once); byte-scatter writes land in L2
// (wq is 256 KB, L2-resident for the gemm).
__global__ __launch_bounds__(256) void wquant_kernel(const float4* __restrict__ wv,
                                                     const unsigned* __restrict__ scales,
                                                     unsigned char* __restrict__ wq) {
    const float ws = 448.0f / fmaxf(__uint_as_float(scales[1]), 1e-12f);
    #pragma unroll
    for (int j = 0; j < 4; ++j) {
        const int idx = blockIdx.x * 1024 + j * 256 + threadIdx.x;  // 65,536 float4 total
        const int k = idx >> 7;          // w row (K), 128 float4 per row
        const int n4 = idx & 127;        // float4 within row
        float4 v = wv[idx];
        float a[4] = {v.x, v.y, v.z, v.w};
        #pragma unroll
        for (int i = 0; i < 4; ++i) {
            float q = clamp448(a[i] * ws);
            int p = __builtin_amdgcn_cvt_pk_fp8_f32(q, q, 0, false);
            wq[(n4 * 4 + i) * KDIM + k] = (unsigned char)(p & 0xff);
        }
    }
}

// ---------------- Kernel 3: fused x-quant (LDS staging) + fp8 MFMA GEMM + dequant ------------
// Block: 64 rows x full K=512. 4 waves, each 64x64 output per n-chunk, 2 chunks of 256 cols.
// Epilogue staged through LDS so global stores are contiguous 1 KB half-rows (full lines).
__global__ __launch_bounds__(256, 4) void gemm_kernel(const float* __restrict__ x,
                                                      const unsigned char* __restrict__ wq,
                                                      const unsigned* __restrict__ scales,
                                                      float* __restrict__ out) {
    __shared__ unsigned char lds_a[64 * LDS_STRIDE];  // 33,280 B
    __shared__ float lds_o[16 * OUT_STRIDE];          // 16,640 B epilogue staging
    const int tid = threadIdx.x;
    const long m0 = (long)blockIdx.x * 64;

    const float ax = fmaxf(__uint_as_float(scales[0]), 1e-12f);
    const float aw = fmaxf(__uint_as_float(scales[1]), 1e-12f);
    const float xs = 448.0f / ax;
    const float ws = 448.0f / aw;
    const float inv = (1.0f / xs) * (1.0f / ws);   // mirror reference dequant arithmetic

    // ---- stage: 64x512 fp32 -> fp8 into LDS (8,192 float4, 32 per thread, coalesced) ----
    const float4* xv = (const float4*)(x + m0 * KDIM);
    #pragma unroll 8
    for (int j = 0; j < 32; ++j) {
        int f4i = tid + 256 * j;
        float4 v = xv[f4i];
        int row = f4i >> 7;             // 128 float4 per row
        int colb = (f4i & 127) << 2;    // byte column
        float a0 = clamp448(v.x * xs);
        float a1 = clamp448(v.y * xs);
        float a2 = clamp448(v.z * xs);
        float a3 = clamp448(v.w * xs);
        int p = __builtin_amdgcn_cvt_pk_fp8_f32(a0, a1, 0, false);
        p = __builtin_amdgcn_cvt_pk_fp8_f32(a2, a3, p, true);
        *(unsigned*)&lds_a[row * LDS_STRIDE + colb] = (unsigned)p;
    }
    __syncthreads();

    const int wave = tid >> 6, lane = tid & 63;
    const int ln = lane & 15, lg = lane >> 4;
    const int kofs = lg * 8;
    float* outp = out + m0 * NDIM;

    for (int chunk = 0; chunk < 2; ++chunk) {
        const int nbase = chunk * 256 + wave * 64;
        f32x4 acc[4][4];
        #pragma unroll
        for (int a = 0; a < 4; ++a)
            #pragma unroll
            for (int b = 0; b < 4; ++b)
                acc[a][b] = (f32x4){0.0f, 0.0f, 0.0f, 0.0f};

        for (int ks = 0; ks < 16; ++ks) {
            const int kb = ks * 32 + kofs;
            i64 af[4], bf[4];
            #pragma unroll
            for (int t = 0; t < 4; ++t)
                af[t] = *(const i64*)&lds_a[(t * 16 + ln) * LDS_STRIDE + kb];
            #pragma unroll
            for (int t = 0; t < 4; ++t)
                bf[t] = *(const i64*)&wq[(nbase + t * 16 + ln) * KDIM + kb];
            #pragma unroll
            for (int tm = 0; tm < 4; ++tm)
                #pragma unroll
                for (int tn = 0; tn < 4; ++tn)
                    acc[tm][tn] = __builtin_amdgcn_mfma_f32_16x16x32_fp8_fp8(
                        af[tm], bf[tn], acc[tm][tn], 0, 0, 0);
        }

        // ---- epilogue: LDS-staged coalesced stores, one 16-row slab at a time ----
        // MFMA C/D layout: col = lane&15, row = (lane>>4)*4 + reg.
        #pragma unroll 1
        for (int tm = 0; tm < 4; ++tm) {
            __syncthreads();   // previous slab's reads done before overwrite
            #pragma unroll
            for (int tn = 0; tn < 4; ++tn) {
                const int c = wave * 64 + tn * 16 + ln;
                #pragma unroll
                for (int r = 0; r < 4; ++r)
                    lds_o[(lg * 4 + r) * OUT_STRIDE + c] = acc[tm][tn][r] * inv;
            }
            __syncthreads();
            // 16 rows x 256 cols = 1024 float4; each wave stores contiguous 1 KB half-rows
            #pragma unroll
            for (int j = 0; j < 4; ++j) {
                const int idx = j * 256 + tid;
                const int rr = idx >> 6;       // 0..15
                const int c4 = idx & 63;       // float4 within half-row
                float4 v = *(const float4*)&lds_o[rr * OUT_STRIDE + c4 * 4];
                *(float4*)&outp[(long)(tm * 16 + rr) * NDIM + chunk * 256 + c4 * 4] = v;
            }
        }
    }
}

extern "C" void kernel_launch(void* const* d_in, const int* in_sizes, int n_in,
                              void* d_out, int out_size, void* d_ws, size_t ws_size,
                              hipStream_t stream) {
    const float* x = (const float*)d_in[0];
    const float* w = (const float*)d_in[1];
    float* out = (float*)d_out;
    unsigned* scales = (unsigned*)d_ws;                 // ws[0]=x_amax bits, ws[1]=w_amax bits
    unsigned char* wq = (unsigned char*)d_ws + 256;     // 262,144 B fp8 weight [N,K]
    const int M = in_sizes[0] / KDIM;                   // 65536

    hipMemsetAsync(d_ws, 0, 8, stream);                 // zero amax slots (ws is poisoned 0xAA)
    amax_kernel<<<4096 + 32, 256, 0, stream>>>((const float4*)x, (const float4*)w, scales);
    wquant_kernel<<<64, 256, 0, stream>>>((const float4*)w, scales, wq);
    gemm_kernel<<<M / 64, 256, 0, stream>>>(x, wq, scales, out);
}